// Round 19
// baseline (143.393 us; speedup 1.0000x reference)
//
#include <hip/hip_runtime.h>

// Fixed problem geometry: D=64, n_gt=512, npg=399 nodes/tree, 398 edges/tree.
#define NPG 399

typedef __bf16 bf16x8 __attribute__((ext_vector_type(8)));
typedef _Float16 half8 __attribute__((ext_vector_type(8)));
typedef float f32x4 __attribute__((ext_vector_type(4)));

__device__ __forceinline__ unsigned short f2bf(float f) {
  unsigned u = __float_as_uint(f);
  unsigned r = (u + 0x7FFFu + ((u >> 16) & 1u)) >> 16;
  return (unsigned short)r;
}
// x rows live in LDS as 8 chunks of 8 f16; chunk slot = chunk ^ (node&7).
__device__ __forceinline__ int xel(int node, int dim) {
  return node * 64 + ((((dim >> 3)) ^ (node & 7)) << 3) + (dim & 7);
}

// Build (a) mf A-fragments (bf16, 16x16x32 lane layout) + packed bitmasks,
// (b) f16 frag-swizzled weight fragments in GLOBAL (L2-resident).
__global__ __launch_bounds__(256) void k_prep(const int* __restrict__ clade,
                                              const float* __restrict__ W1,
                                              const float* __restrict__ W2,
                                              unsigned short* __restrict__ mfA,
                                              unsigned* __restrict__ mfbits,
                                              _Float16* __restrict__ wswz,
                                              int n_edges, int n_species) {
  int stride = gridDim.x * 256;
  for (int idx = blockIdx.x * 256 + threadIdx.x; idx < 25 * 7 * 512;
       idx += stride) {
    int fi = idx >> 9, within = idx & 511;
    int mt = fi / 7, kt = fi % 7;
    int l = within >> 3, j = within & 7;
    int e = mt * 16 + (l & 15);
    int s = kt * 32 + ((l >> 4) & 3) * 8 + j;
    unsigned short v = 0;
    if (e < n_edges && s < n_species && clade[(size_t)e * n_species + s] != 0)
      v = 0x3F80;  // bf16(1.0)
    mfA[idx] = v;
  }
  for (int idx = blockIdx.x * 256 + threadIdx.x; idx < 400 * 8; idx += stride) {
    int e = idx >> 3, w = idx & 7;
    unsigned bits = 0;
    if (e < n_edges && w < 7) {
      for (int b = 0; b < 32; ++b) {
        int s = w * 32 + b;
        if (s < n_species && clade[(size_t)e * n_species + s] != 0)
          bits |= 1u << b;
      }
    }
    mfbits[idx] = bits;
  }
  for (int idx = blockIdx.x * 256 + threadIdx.x; idx < 16384; idx += stride) {
    int li = idx >> 12;  // 0..3 = (layer<<1)|mat
    int k = (idx >> 6) & 63, n = idx & 63;
    int frag = (k >> 5) * 4 + (n >> 4);
    int ln = ((k >> 3) & 3) * 16 + (n & 15);
    int j = k & 7;
    int l = li >> 1;
    const float* Ws = (li & 1) ? W2 : W1;
    wswz[li * 4096 + frag * 512 + ln * 8 + j] =
        (_Float16)Ws[l * 4096 + k * 64 + n];
  }
}

// Mega-kernel v10: one block per gene tree, 8 waves, LDS ~74 KB -> 2 blocks/CU
// (4 waves/SIMD). Single LDS x buffer; layer outputs go via per-wave tile buf
// -> coalesced global gx -> staged back swizzled. Weights from global wswz.
__global__ __launch_bounds__(512, 4) void k_tree(
    const float* __restrict__ emb, const int* __restrict__ sp,
    const int* __restrict__ leaf, const int* __restrict__ src,
    const int* __restrict__ dst, const _Float16* __restrict__ wswz,
    const float* __restrict__ b1, const float* __restrict__ b2,
    const float* __restrict__ eps_p, const float* __restrict__ gam,
    const float* __restrict__ bet, _Float16* __restrict__ gx,
    unsigned short* __restrict__ pool_swz, unsigned* __restrict__ valid_bits,
    int npg, int n_species) {
  __shared__ __attribute__((aligned(16))) _Float16 sA[NPG * 64];
  __shared__ __attribute__((aligned(16))) _Float16 sT[8][1024];
  __shared__ int sStart[NPG + 1];
  __shared__ int sChild[NPG - 1];
  __shared__ int sPar[NPG];
  __shared__ int sCnt[NPG];

  int g = blockIdx.x, tid = threadIdx.x;
  int base = g * npg, nEt = npg - 1, ebase = g * nEt;
  int w = tid >> 6, lane = tid & 63;
  int cc = lane & 15, gq = lane >> 4;

  // ---- 0a: zero CSR counters
  for (int i = tid; i < npg + 1; i += 512) sStart[i] = 0;
  for (int i = tid; i < npg; i += 512) sCnt[i] = 0;
  __syncthreads();
  // ---- 0b: emb gather (swizzled chunks), edges + histogram
  for (int idx = tid; idx < npg * 8; idx += 512) {
    int node = idx >> 3, ch = idx & 7;
    int s = sp[base + node];
    int row = (s < 0) ? n_species : s;
    float4 v0 = reinterpret_cast<const float4*>(emb)[row * 16 + ch * 2];
    float4 v1 = reinterpret_cast<const float4*>(emb)[row * 16 + ch * 2 + 1];
    half8 h;
    h[0] = (_Float16)v0.x; h[1] = (_Float16)v0.y;
    h[2] = (_Float16)v0.z; h[3] = (_Float16)v0.w;
    h[4] = (_Float16)v1.x; h[5] = (_Float16)v1.y;
    h[6] = (_Float16)v1.z; h[7] = (_Float16)v1.w;
    *reinterpret_cast<half8*>(&sA[node * 64 + ((ch ^ (node & 7)) << 3)]) = h;
  }
  for (int i = tid; i < nEt; i += 512) {
    int c = src[ebase + i] - base;
    int p = dst[ebase + i] - base;
    sPar[c] = p;
    atomicAdd(&sStart[p + 1], 1);
  }
  __syncthreads();
  // ---- 0c: inclusive scan (wave 0, shfl)
  if (w == 0) {
    int run = 0;
    for (int chunk = 0; chunk * 64 < npg + 1; ++chunk) {
      int idx = chunk * 64 + lane;
      int v = (idx < npg + 1) ? sStart[idx] : 0;
      for (int off = 1; off < 64; off <<= 1) {
        int t2 = __shfl_up(v, off);
        if (lane >= off) v += t2;
      }
      v += run;
      if (idx < npg + 1) sStart[idx] = v;
      run = __shfl(v, 63);
    }
  }
  __syncthreads();
  // ---- 0d: scatter children
  for (int c = tid + 1; c < npg; c += 512) {
    int p = sPar[c];
    int pos = sStart[p] + atomicAdd(&sCnt[p], 1);
    sChild[pos] = c;
  }
  __syncthreads();

  // ---- layers: read sA, output via tb -> gx (coalesced), stage back to sA
  _Float16* tb = sT[w];
  int t0w = w * 3;
  int t1w = (w == 7) ? 25 : t0w + 3;
  const half8* xin8 = reinterpret_cast<const half8*>(sA);
  _Float16* gxg = gx + (size_t)base * 64;
  half8* gxg8 = reinterpret_cast<half8*>(gxg);
  for (int l = 0; l < 2; ++l) {
    float e1 = 1.0f + eps_p[l];
    float b1v[4], b2v[4], gv[4], bv[4];
#pragma unroll
    for (int nt = 0; nt < 4; ++nt) {
      b1v[nt] = b1[l * 64 + cc + 16 * nt];
      b2v[nt] = b2[l * 64 + cc + 16 * nt];
      gv[nt] = gam[l * 64 + cc + 16 * nt];
      bv[nt] = bet[l * 64 + cc + 16 * nt];
    }
    const half8* B1 = reinterpret_cast<const half8*>(wswz + (l * 2 + 0) * 4096);
    const half8* B2 = reinterpret_cast<const half8*>(wswz + (l * 2 + 1) * 4096);
    for (int t = t0w; t < t1w; ++t) {
      int n0 = t * 16;
      // lane-parallel msg gather; accumulator IS the A-fragment (f32)
      int node = n0 + cc;
      bool vn = node < npg;
      int nd2 = vn ? node : 0;
      int j0v = vn ? sStart[nd2] : 0;
      int cnt = vn ? (sStart[nd2 + 1] - j0v) : 0;
      half8 s0 = xin8[nd2 * 8 + (gq ^ (nd2 & 7))];
      half8 s1 = xin8[nd2 * 8 + ((4 + gq) ^ (nd2 & 7))];
      bool hasp = vn && node > 0;
      int pr = hasp ? sPar[nd2] : 0;
      half8 p0 = xin8[pr * 8 + (gq ^ (pr & 7))];
      half8 p1 = xin8[pr * 8 + ((4 + gq) ^ (pr & 7))];
      float a0f[8], a1f[8];
#pragma unroll
      for (int d = 0; d < 8; ++d) {
        a0f[d] = e1 * (float)s0[d] + (hasp ? (float)p0[d] : 0.f);
        a1f[d] = e1 * (float)s1[d] + (hasp ? (float)p1[d] : 0.f);
      }
      int cmax = cnt;
#pragma unroll
      for (int off = 1; off < 64; off <<= 1)
        cmax = max(cmax, __shfl_xor(cmax, off));
      cmax = __builtin_amdgcn_readfirstlane(cmax);
#pragma unroll 2
      for (int k = 0; k < cmax; ++k) {
        bool act = k < cnt;
        int jidx = act ? (j0v + k) : 0;
        int c = sChild[jidx];
        half8 v0 = xin8[c * 8 + (gq ^ (c & 7))];
        half8 v1 = xin8[c * 8 + ((4 + gq) ^ (c & 7))];
        if (act) {
#pragma unroll
          for (int d = 0; d < 8; ++d) {
            a0f[d] += (float)v0[d];
            a1f[d] += (float)v1[d];
          }
        }
      }
      half8 a0, a1;
#pragma unroll
      for (int d = 0; d < 8; ++d) {
        a0[d] = (_Float16)a0f[d];
        a1[d] = (_Float16)a1f[d];
      }
      // MFMA 1 + relu -> per-wave tile buffer (XOR-swizzled)
      f32x4 tacc[4];
#pragma unroll
      for (int nt = 0; nt < 4; ++nt) tacc[nt] = (f32x4){0.f, 0.f, 0.f, 0.f};
#pragma unroll
      for (int nt = 0; nt < 4; ++nt) {
        tacc[nt] = __builtin_amdgcn_mfma_f32_16x16x32_f16(
            a0, B1[nt * 64 + lane], tacc[nt], 0, 0, 0);
        tacc[nt] = __builtin_amdgcn_mfma_f32_16x16x32_f16(
            a1, B1[(4 + nt) * 64 + lane], tacc[nt], 0, 0, 0);
      }
#pragma unroll
      for (int nt = 0; nt < 4; ++nt)
#pragma unroll
        for (int r = 0; r < 4; ++r) {
          int m = gq * 4 + r;
          tb[m * 64 + ((cc + 16 * nt) ^ ((m & 7) << 3))] =
              (_Float16)fmaxf(tacc[nt][r] + b1v[nt], 0.f);
        }
      int sw = (cc & 7) << 3;
      half8 c0 =
          *reinterpret_cast<const half8*>(&tb[cc * 64 + ((gq * 8) ^ sw)]);
      half8 c1 =
          *reinterpret_cast<const half8*>(&tb[cc * 64 + ((32 + gq * 8) ^ sw)]);
      f32x4 hacc[4];
#pragma unroll
      for (int nt = 0; nt < 4; ++nt) hacc[nt] = (f32x4){0.f, 0.f, 0.f, 0.f};
#pragma unroll
      for (int nt = 0; nt < 4; ++nt) {
        hacc[nt] = __builtin_amdgcn_mfma_f32_16x16x32_f16(
            c0, B2[nt * 64 + lane], hacc[nt], 0, 0, 0);
        hacc[nt] = __builtin_amdgcn_mfma_f32_16x16x32_f16(
            c1, B2[(4 + nt) * 64 + lane], hacc[nt], 0, 0, 0);
      }
      // residual + LayerNorm (f32) -> tb (swizzled) -> coalesced gx
      float y[4][4];
#pragma unroll
      for (int r = 0; r < 4; ++r) {
        int nd3 = n0 + gq * 4 + r;
        bool v3 = nd3 < npg;
        int nds = v3 ? nd3 : 0;
#pragma unroll
        for (int nt = 0; nt < 4; ++nt) {
          float xv = (float)sA[xel(nds, cc + 16 * nt)];
          y[r][nt] = (v3 ? xv : 0.f) + hacc[nt][r] + b2v[nt];
        }
      }
#pragma unroll
      for (int r = 0; r < 4; ++r) {
        float s = y[r][0] + y[r][1] + y[r][2] + y[r][3];
        s += __shfl_xor(s, 1);
        s += __shfl_xor(s, 2);
        s += __shfl_xor(s, 4);
        s += __shfl_xor(s, 8);
        float mu = s * (1.f / 64.f);
        float d0 = y[r][0] - mu, d1 = y[r][1] - mu;
        float d2 = y[r][2] - mu, d3 = y[r][3] - mu;
        float v = d0 * d0 + d1 * d1 + d2 * d2 + d3 * d3;
        v += __shfl_xor(v, 1);
        v += __shfl_xor(v, 2);
        v += __shfl_xor(v, 4);
        v += __shfl_xor(v, 8);
        float iv = rsqrtf(v * (1.f / 64.f) + 1e-5f);
        int m = gq * 4 + r;
#pragma unroll
        for (int nt = 0; nt < 4; ++nt)
          tb[m * 64 + ((cc + 16 * nt) ^ ((m & 7) << 3))] =
              (_Float16)((y[r][nt] - mu) * iv * gv[nt] + bv[nt]);
      }
      // copy-out tile: tb (swizzled) -> gx linear, coalesced half8 stores
#pragma unroll
      for (int it = 0; it < 2; ++it) {
        int idx = it * 64 + lane;
        int m = idx >> 3, ch = idx & 7;
        int nd = n0 + m;
        if (nd < npg)
          gxg8[nd * 8 + ch] = *reinterpret_cast<const half8*>(
              &tb[m * 64 + ((ch ^ (m & 7)) << 3)]);
      }
    }
    __syncthreads();
    // stage back gx -> sA (swizzled chunks), coalesced reads
    for (int idx = tid; idx < npg * 8; idx += 512) {
      int node = idx >> 3, ch = idx & 7;
      *reinterpret_cast<half8*>(&sA[node * 64 + ((ch ^ (node & 7)) << 3)]) =
          gxg8[node * 8 + ch];
    }
    __syncthreads();
  }

  // ---- 3: species pooling (final x in sA); lists reuse CSR arrays; means
  //         written frag-swizzled bf16 to GLOBAL pool_swz.
  for (int i = tid; i < n_species + 1; i += 512) sStart[i] = 0;
  for (int i = tid; i < n_species; i += 512) sCnt[i] = 0;
  __syncthreads();
  for (int i = tid; i < npg; i += 512) {
    int s = sp[base + i];
    if (s >= 0 && leaf[base + i] != 0) atomicAdd(&sStart[s + 1], 1);
  }
  __syncthreads();
  if (w == 0) {
    int run = 0;
    for (int chunk = 0; chunk * 64 < n_species + 1; ++chunk) {
      int idx = chunk * 64 + lane;
      int v = (idx < n_species + 1) ? sStart[idx] : 0;
      for (int off = 1; off < 64; off <<= 1) {
        int t2 = __shfl_up(v, off);
        if (lane >= off) v += t2;
      }
      v += run;
      if (idx < n_species + 1) sStart[idx] = v;
      run = __shfl(v, 63);
    }
  }
  __syncthreads();
  for (int i = tid; i < npg; i += 512) {
    int s = sp[base + i];
    if (s >= 0 && leaf[base + i] != 0) {
      int pos = sStart[s] + atomicAdd(&sCnt[s], 1);
      sPar[pos] = i;
    }
  }
  __syncthreads();
  unsigned short* pg = pool_swz + (size_t)g * 14336;
  for (int idx = tid; idx < 224 * 8; idx += 512) {
    int s = idx >> 3, dc = idx & 7;
    float sum[8] = {0.f, 0.f, 0.f, 0.f, 0.f, 0.f, 0.f, 0.f};
    int cntv = 0;
    if (s < n_species) {
      int j0 = sStart[s], j1 = sStart[s + 1];
      cntv = j1 - j0;
      for (int j2 = j0; j2 < j1; ++j2) {
        int nd = sPar[j2];
        half8 v = *reinterpret_cast<const half8*>(
            &sA[nd * 64 + ((dc ^ (nd & 7)) << 3)]);
#pragma unroll
        for (int dd = 0; dd < 8; ++dd) sum[dd] += (float)v[dd];
      }
    }
    float invc = (cntv > 0) ? 1.f / (float)cntv : 0.f;
#pragma unroll
    for (int dd = 0; dd < 8; ++dd) {
      int d = dc * 8 + dd;
      int frag = (s >> 5) * 4 + (d >> 4);
      int ln = ((s >> 3) & 3) * 16 + (d & 15);
      pg[frag * 512 + ln * 8 + (s & 7)] = f2bf(sum[dd] * invc);
    }
  }
  if (tid < 7) {
    unsigned bits = 0;
    for (int b = 0; b < 32; ++b) {
      int s = tid * 32 + b;
      if (s < n_species && sStart[s + 1] > sStart[s]) bits |= 1u << b;
    }
    valid_bits[(size_t)g * 8 + tid] = bits;
  }
}

// Clade-sum MFMA: one block per gene tree (f16 gmat output).
__global__ __launch_bounds__(512) void k_gm2(
    const unsigned short* __restrict__ pool_swz,
    const unsigned* __restrict__ valid_bits,
    const unsigned short* __restrict__ mfA, const unsigned* __restrict__ mfbits,
    _Float16* __restrict__ gmat, float* __restrict__ has, int n_edges,
    int n_gt) {
  __shared__ __attribute__((aligned(16))) unsigned short sBf[14336];
  __shared__ float sInv[400];
  __shared__ float sHas[400];
  int g = blockIdx.x;
  int tid = threadIdx.x;
  const float4* src4 =
      reinterpret_cast<const float4*>(pool_swz + (size_t)g * 14336);
  float4* dst4 = reinterpret_cast<float4*>(sBf);
  for (int i = tid; i < 1792; i += 512) dst4[i] = src4[i];
  unsigned vb[7];
#pragma unroll
  for (int w2 = 0; w2 < 7; ++w2) vb[w2] = valid_bits[(size_t)g * 8 + w2];
  for (int e = tid; e < 400; e += 512) {
    unsigned cc = 0;
#pragma unroll
    for (int w2 = 0; w2 < 7; ++w2) cc += __popc(mfbits[e * 8 + w2] & vb[w2]);
    sInv[e] = 1.f / (float)max(cc, 1u);
    sHas[e] = (cc > 0) ? 1.f : 0.f;
  }
  __syncthreads();
  int w = tid >> 6, lane = tid & 63;
  const bf16x8* A = reinterpret_cast<const bf16x8*>(mfA);
  const bf16x8* Bb = reinterpret_cast<const bf16x8*>(sBf);
  for (int mt = w; mt < 25; mt += 8) {
    bf16x8 af[7];
#pragma unroll
    for (int kt = 0; kt < 7; ++kt) af[kt] = A[(mt * 7 + kt) * 64 + lane];
    f32x4 acc0 = {0.f, 0.f, 0.f, 0.f};
    f32x4 acc1 = {0.f, 0.f, 0.f, 0.f};
    f32x4 acc2 = {0.f, 0.f, 0.f, 0.f};
    f32x4 acc3 = {0.f, 0.f, 0.f, 0.f};
#pragma unroll
    for (int kt = 0; kt < 7; ++kt) {
      const bf16x8* B = Bb + kt * 256 + lane;
      acc0 = __builtin_amdgcn_mfma_f32_16x16x32_bf16(af[kt], B[0], acc0, 0, 0, 0);
      acc1 = __builtin_amdgcn_mfma_f32_16x16x32_bf16(af[kt], B[64], acc1, 0, 0, 0);
      acc2 = __builtin_amdgcn_mfma_f32_16x16x32_bf16(af[kt], B[128], acc2, 0, 0, 0);
      acc3 = __builtin_amdgcn_mfma_f32_16x16x32_bf16(af[kt], B[192], acc3, 0, 0, 0);
    }
    int rbase = mt * 16 + (lane >> 4) * 4;
    int col = lane & 15;
#pragma unroll
    for (int r = 0; r < 4; ++r) {
      int e = rbase + r;
      if (e >= n_edges) continue;
      float inv = sInv[e];
      _Float16* gp = gmat + ((size_t)e * n_gt + g) * 64 + col;
      gp[0] = (_Float16)(acc0[r] * inv);
      gp[16] = (_Float16)(acc1[r] * inv);
      gp[32] = (_Float16)(acc2[r] * inv);
      gp[48] = (_Float16)(acc3[r] * inv);
      if (col == 0) has[(size_t)e * n_gt + g] = sHas[e];
    }
  }
}

// Partial mean/std over a quarter of the gene trees per block.
__global__ __launch_bounds__(256) void k_stat2(const _Float16* __restrict__ gmat,
                                               const float* __restrict__ has,
                                               float* __restrict__ part,
                                               int n_gt) {
  __shared__ float red1[4][64];
  __shared__ float red2[4][64];
  __shared__ float redn[4];
  int b = blockIdx.x;
  int e = b >> 2, q = b & 3;
  int tid = threadIdx.x, w = tid >> 6, lane = tid & 63;
  const _Float16* ge = gmat + ((size_t)e * n_gt + q * 128) * 64;
  const float* he = has + (size_t)e * n_gt + q * 128;
  float S1 = 0.f, S2 = 0.f, nv = 0.f;
  for (int i = w; i < 128; i += 4) {
    float h = he[i];
    float v = (float)ge[i * 64 + lane];
    S1 += h * v;
    S2 += h * v * v;
    nv += h;
  }
  red1[w][lane] = S1;
  red2[w][lane] = S2;
  if (lane == 0) redn[w] = nv;
  __syncthreads();
  if (w == 0) {
    float s1 = 0.f, s2 = 0.f, n_v = 0.f;
#pragma unroll
    for (int j = 0; j < 4; ++j) {
      s1 += red1[j][lane];
      s2 += red2[j][lane];
      n_v += redn[j];
    }
    float* p = part + (size_t)b * 130;
    p[lane] = s1;
    p[64 + lane] = s2;
    if (lane == 0) p[128] = n_v;
  }
}

// Combine the 4 partials per edge and finalize mean/std.
__global__ __launch_bounds__(64) void k_fin(const float* __restrict__ part,
                                            float* __restrict__ out) {
  int e = blockIdx.x;
  int lane = threadIdx.x;
  float s1 = 0.f, s2 = 0.f, n_v = 0.f;
#pragma unroll
  for (int q = 0; q < 4; ++q) {
    const float* p = part + (size_t)(e * 4 + q) * 130;
    s1 += p[lane];
    s2 += p[64 + lane];
    n_v += p[128];
  }
  float mean = s1 / fmaxf(n_v, 1.f);
  float var = (s2 - s1 * s1 / fmaxf(n_v, 1.f)) / fmaxf(n_v - 1.f, 1.f);
  float stdv = (n_v > 1.f) ? sqrtf(fmaxf(var, 0.f)) : 0.f;
  out[(size_t)e * 128 + lane] = (n_v > 0.f) ? mean : 0.f;
  out[(size_t)e * 128 + 64 + lane] = stdv;
}

extern "C" void kernel_launch(void* const* d_in, const int* in_sizes, int n_in,
                              void* d_out, int out_size, void* d_ws, size_t ws_size,
                              hipStream_t stream) {
  (void)n_in; (void)out_size; (void)ws_size;
  const int* edge_index = (const int*)d_in[0];
  const int* sp_ids = (const int*)d_in[1];
  const int* leaf_mask = (const int*)d_in[2];
  const int* clade_mask = (const int*)d_in[4];
  const float* emb = (const float*)d_in[6];
  const float* W1 = (const float*)d_in[7];
  const float* b1 = (const float*)d_in[8];
  const float* W2 = (const float*)d_in[9];
  const float* b2 = (const float*)d_in[10];
  const float* eps = (const float*)d_in[11];
  const float* lng = (const float*)d_in[12];
  const float* lnb = (const float*)d_in[13];
  float* out = (float*)d_out;

  const int n_nodes = in_sizes[1];             // 204288
  const int nE = in_sizes[0] / 2;              // 407552 directed edges
  const int n_species = in_sizes[6] / 64 - 1;  // 200
  const int n_edges = in_sizes[4] / n_species; // 397
  const int n_gt = 512;                        // fixed problem size
  const int npg = n_nodes / n_gt;              // 399 nodes per gene tree

  const int* src = edge_index;       // first half: child ids
  const int* dst = edge_index + nE;  // first half: parent ids

  char* p = (char*)d_ws;
  _Float16* gmat = (_Float16*)p;
  p += ((size_t)n_edges * n_gt * 64 * sizeof(_Float16) + 255ul) & ~255ul;
  float* has = (float*)p;
  p += ((size_t)n_edges * n_gt * sizeof(float) + 255ul) & ~255ul;
  unsigned short* mfA = (unsigned short*)p;
  p += ((size_t)25 * 7 * 512 * sizeof(unsigned short) + 255ul) & ~255ul;
  unsigned* mfbits = (unsigned*)p;
  p += ((size_t)400 * 8 * sizeof(unsigned) + 255ul) & ~255ul;
  float* part = (float*)p;
  p += ((size_t)n_edges * 4 * 130 * sizeof(float) + 255ul) & ~255ul;
  unsigned short* pool_swz = (unsigned short*)p;
  p += ((size_t)n_gt * 14336 * sizeof(unsigned short) + 255ul) & ~255ul;
  unsigned* valid_bits = (unsigned*)p;
  p += ((size_t)n_gt * 8 * sizeof(unsigned) + 255ul) & ~255ul;
  _Float16* wswz = (_Float16*)p;
  p += ((size_t)16384 * sizeof(_Float16) + 255ul) & ~255ul;
  _Float16* gx = (_Float16*)p;

  k_prep<<<64, 256, 0, stream>>>(clade_mask, W1, W2, mfA, mfbits, wswz,
                                 n_edges, n_species);
  k_tree<<<n_gt, 512, 0, stream>>>(emb, sp_ids, leaf_mask, src, dst, wswz, b1,
                                   b2, eps, lng, lnb, gx, pool_swz, valid_bits,
                                   npg, n_species);
  k_gm2<<<n_gt, 512, 0, stream>>>(pool_swz, valid_bits, mfA, mfbits, gmat,
                                  has, n_edges, n_gt);
  k_stat2<<<n_edges * 4, 256, 0, stream>>>(gmat, has, part, n_gt);
  k_fin<<<n_edges, 64, 0, stream>>>(part, out);
}

// Round 20
// 115.967 us; speedup vs baseline: 1.2365x; 1.2365x over previous
//
#include <hip/hip_runtime.h>

// Fixed problem geometry: D=64, n_gt=512, npg=399 nodes/tree, 398 edges/tree.
#define NPG 399

typedef __bf16 bf16x8 __attribute__((ext_vector_type(8)));
typedef _Float16 half8 __attribute__((ext_vector_type(8)));
typedef float f32x4 __attribute__((ext_vector_type(4)));

__device__ __forceinline__ unsigned short f2bf(float f) {
  unsigned u = __float_as_uint(f);
  unsigned r = (u + 0x7FFFu + ((u >> 16) & 1u)) >> 16;
  return (unsigned short)r;
}
// x rows live in LDS as 8 chunks of 8 f16; chunk slot = chunk ^ (node&7).
__device__ __forceinline__ int xel(int node, int dim) {
  return node * 64 + ((((dim >> 3)) ^ (node & 7)) << 3) + (dim & 7);
}

// Build (a) mf A-fragments (bf16, 16x16x32 lane layout) + packed bitmasks,
// (b) f16 frag-swizzled weight fragments in GLOBAL (L2-resident).
__global__ __launch_bounds__(256) void k_prep(const int* __restrict__ clade,
                                              const float* __restrict__ W1,
                                              const float* __restrict__ W2,
                                              unsigned short* __restrict__ mfA,
                                              unsigned* __restrict__ mfbits,
                                              _Float16* __restrict__ wswz,
                                              int n_edges, int n_species) {
  int stride = gridDim.x * 256;
  for (int idx = blockIdx.x * 256 + threadIdx.x; idx < 25 * 7 * 512;
       idx += stride) {
    int fi = idx >> 9, within = idx & 511;
    int mt = fi / 7, kt = fi % 7;
    int l = within >> 3, j = within & 7;
    int e = mt * 16 + (l & 15);
    int s = kt * 32 + ((l >> 4) & 3) * 8 + j;
    unsigned short v = 0;
    if (e < n_edges && s < n_species && clade[(size_t)e * n_species + s] != 0)
      v = 0x3F80;  // bf16(1.0)
    mfA[idx] = v;
  }
  for (int idx = blockIdx.x * 256 + threadIdx.x; idx < 400 * 8; idx += stride) {
    int e = idx >> 3, w = idx & 7;
    unsigned bits = 0;
    if (e < n_edges && w < 7) {
      for (int b = 0; b < 32; ++b) {
        int s = w * 32 + b;
        if (s < n_species && clade[(size_t)e * n_species + s] != 0)
          bits |= 1u << b;
      }
    }
    mfbits[idx] = bits;
  }
  for (int idx = blockIdx.x * 256 + threadIdx.x; idx < 16384; idx += stride) {
    int li = idx >> 12;  // 0..3 = (layer<<1)|mat
    int k = (idx >> 6) & 63, n = idx & 63;
    int frag = (k >> 5) * 4 + (n >> 4);
    int ln = ((k >> 3) & 3) * 16 + (n & 15);
    int j = k & 7;
    int l = li >> 1;
    const float* Ws = (li & 1) ? W2 : W1;
    wswz[li * 4096 + frag * 512 + ln * 8 + j] =
        (_Float16)Ws[l * 4096 + k * 64 + n];
  }
}

// Mega-kernel v11 = r18's k_tree (84us: weights from global, sA/sB resident)
// + fused clade-MFMA tail (sBf aliases dead sB; aux aliases dead sT).
__global__ __launch_bounds__(512) void k_tree(
    const float* __restrict__ emb, const int* __restrict__ sp,
    const int* __restrict__ leaf, const int* __restrict__ src,
    const int* __restrict__ dst, const _Float16* __restrict__ wswz,
    const float* __restrict__ b1, const float* __restrict__ b2,
    const float* __restrict__ eps_p, const float* __restrict__ gam,
    const float* __restrict__ bet, const unsigned short* __restrict__ mfA,
    const unsigned* __restrict__ mfbits, _Float16* __restrict__ gmat,
    float* __restrict__ has, int npg, int n_species, int n_edges, int n_gt) {
  __shared__ __attribute__((aligned(16))) _Float16 sA[NPG * 64];
  __shared__ __attribute__((aligned(16))) _Float16 sB[NPG * 64];
  __shared__ __attribute__((aligned(16))) _Float16 sT[8][1024];
  __shared__ int sStart[NPG + 1];
  __shared__ int sChild[NPG - 1];
  __shared__ int sPar[NPG];
  __shared__ int sCnt[NPG];

  int g = blockIdx.x, tid = threadIdx.x;
  int base = g * npg, nEt = npg - 1, ebase = g * nEt;
  int w = tid >> 6, lane = tid & 63;
  int cc = lane & 15, gq = lane >> 4;

  // ---- 0a: zero CSR counters
  for (int i = tid; i < npg + 1; i += 512) sStart[i] = 0;
  for (int i = tid; i < npg; i += 512) sCnt[i] = 0;
  __syncthreads();
  // ---- 0b: emb gather (swizzled chunks), edges + histogram
  for (int idx = tid; idx < npg * 8; idx += 512) {
    int node = idx >> 3, ch = idx & 7;
    int s = sp[base + node];
    int row = (s < 0) ? n_species : s;
    float4 v0 = reinterpret_cast<const float4*>(emb)[row * 16 + ch * 2];
    float4 v1 = reinterpret_cast<const float4*>(emb)[row * 16 + ch * 2 + 1];
    half8 h;
    h[0] = (_Float16)v0.x; h[1] = (_Float16)v0.y;
    h[2] = (_Float16)v0.z; h[3] = (_Float16)v0.w;
    h[4] = (_Float16)v1.x; h[5] = (_Float16)v1.y;
    h[6] = (_Float16)v1.z; h[7] = (_Float16)v1.w;
    *reinterpret_cast<half8*>(&sA[node * 64 + ((ch ^ (node & 7)) << 3)]) = h;
  }
  for (int i = tid; i < nEt; i += 512) {
    int c = src[ebase + i] - base;
    int p = dst[ebase + i] - base;
    sPar[c] = p;
    atomicAdd(&sStart[p + 1], 1);
  }
  __syncthreads();
  // ---- 0c: inclusive scan (wave 0, shfl)
  if (w == 0) {
    int run = 0;
    for (int chunk = 0; chunk * 64 < npg + 1; ++chunk) {
      int idx = chunk * 64 + lane;
      int v = (idx < npg + 1) ? sStart[idx] : 0;
      for (int off = 1; off < 64; off <<= 1) {
        int t2 = __shfl_up(v, off);
        if (lane >= off) v += t2;
      }
      v += run;
      if (idx < npg + 1) sStart[idx] = v;
      run = __shfl(v, 63);
    }
  }
  __syncthreads();
  // ---- 0d: scatter children
  for (int c = tid + 1; c < npg; c += 512) {
    int p = sPar[c];
    int pos = sStart[p] + atomicAdd(&sCnt[p], 1);
    sChild[pos] = c;
  }
  __syncthreads();

  // ---- layers
  _Float16* tb = sT[w];
  int t0w = w * 3;
  int t1w = (w == 7) ? 25 : t0w + 3;
  for (int l = 0; l < 2; ++l) {
    const _Float16* xin = l ? sB : sA;
    _Float16* xout = l ? sA : sB;
    const half8* xin8 = reinterpret_cast<const half8*>(xin);
    float e1 = 1.0f + eps_p[l];
    float b1v[4], b2v[4], gv[4], bv[4];
#pragma unroll
    for (int nt = 0; nt < 4; ++nt) {
      b1v[nt] = b1[l * 64 + cc + 16 * nt];
      b2v[nt] = b2[l * 64 + cc + 16 * nt];
      gv[nt] = gam[l * 64 + cc + 16 * nt];
      bv[nt] = bet[l * 64 + cc + 16 * nt];
    }
    const half8* B1 = reinterpret_cast<const half8*>(wswz + (l * 2 + 0) * 4096);
    const half8* B2 = reinterpret_cast<const half8*>(wswz + (l * 2 + 1) * 4096);
    for (int t = t0w; t < t1w; ++t) {
      int n0 = t * 16;
      // lane-parallel msg gather; accumulator IS the A-fragment (f32)
      int node = n0 + cc;
      bool vn = node < npg;
      int nd2 = vn ? node : 0;
      int j0v = vn ? sStart[nd2] : 0;
      int cnt = vn ? (sStart[nd2 + 1] - j0v) : 0;
      half8 s0 = xin8[nd2 * 8 + (gq ^ (nd2 & 7))];
      half8 s1 = xin8[nd2 * 8 + ((4 + gq) ^ (nd2 & 7))];
      bool hasp = vn && node > 0;
      int pr = hasp ? sPar[nd2] : 0;
      half8 p0 = xin8[pr * 8 + (gq ^ (pr & 7))];
      half8 p1 = xin8[pr * 8 + ((4 + gq) ^ (pr & 7))];
      float a0f[8], a1f[8];
#pragma unroll
      for (int d = 0; d < 8; ++d) {
        a0f[d] = e1 * (float)s0[d] + (hasp ? (float)p0[d] : 0.f);
        a1f[d] = e1 * (float)s1[d] + (hasp ? (float)p1[d] : 0.f);
      }
      int cmax = cnt;
#pragma unroll
      for (int off = 1; off < 64; off <<= 1)
        cmax = max(cmax, __shfl_xor(cmax, off));
      cmax = __builtin_amdgcn_readfirstlane(cmax);
#pragma unroll 2
      for (int k = 0; k < cmax; ++k) {
        bool act = k < cnt;
        int jidx = act ? (j0v + k) : 0;
        int c = sChild[jidx];
        half8 v0 = xin8[c * 8 + (gq ^ (c & 7))];
        half8 v1 = xin8[c * 8 + ((4 + gq) ^ (c & 7))];
        if (act) {
#pragma unroll
          for (int d = 0; d < 8; ++d) {
            a0f[d] += (float)v0[d];
            a1f[d] += (float)v1[d];
          }
        }
      }
      half8 a0, a1;
#pragma unroll
      for (int d = 0; d < 8; ++d) {
        a0[d] = (_Float16)a0f[d];
        a1[d] = (_Float16)a1f[d];
      }
      // MFMA 1 + relu -> per-wave tile buffer (XOR-swizzled)
      f32x4 tacc[4];
#pragma unroll
      for (int nt = 0; nt < 4; ++nt) tacc[nt] = (f32x4){0.f, 0.f, 0.f, 0.f};
#pragma unroll
      for (int nt = 0; nt < 4; ++nt) {
        tacc[nt] = __builtin_amdgcn_mfma_f32_16x16x32_f16(
            a0, B1[nt * 64 + lane], tacc[nt], 0, 0, 0);
        tacc[nt] = __builtin_amdgcn_mfma_f32_16x16x32_f16(
            a1, B1[(4 + nt) * 64 + lane], tacc[nt], 0, 0, 0);
      }
#pragma unroll
      for (int nt = 0; nt < 4; ++nt)
#pragma unroll
        for (int r = 0; r < 4; ++r) {
          int m = gq * 4 + r;
          tb[m * 64 + ((cc + 16 * nt) ^ ((m & 7) << 3))] =
              (_Float16)fmaxf(tacc[nt][r] + b1v[nt], 0.f);
        }
      int sw = (cc & 7) << 3;
      half8 c0 =
          *reinterpret_cast<const half8*>(&tb[cc * 64 + ((gq * 8) ^ sw)]);
      half8 c1 =
          *reinterpret_cast<const half8*>(&tb[cc * 64 + ((32 + gq * 8) ^ sw)]);
      f32x4 hacc[4];
#pragma unroll
      for (int nt = 0; nt < 4; ++nt) hacc[nt] = (f32x4){0.f, 0.f, 0.f, 0.f};
#pragma unroll
      for (int nt = 0; nt < 4; ++nt) {
        hacc[nt] = __builtin_amdgcn_mfma_f32_16x16x32_f16(
            c0, B2[nt * 64 + lane], hacc[nt], 0, 0, 0);
        hacc[nt] = __builtin_amdgcn_mfma_f32_16x16x32_f16(
            c1, B2[(4 + nt) * 64 + lane], hacc[nt], 0, 0, 0);
      }
      // residual + LayerNorm (f32)
      float y[4][4];
#pragma unroll
      for (int r = 0; r < 4; ++r) {
        int nd3 = n0 + gq * 4 + r;
        bool v3 = nd3 < npg;
        int nds = v3 ? nd3 : 0;
#pragma unroll
        for (int nt = 0; nt < 4; ++nt) {
          float xv = (float)xin[xel(nds, cc + 16 * nt)];
          y[r][nt] = (v3 ? xv : 0.f) + hacc[nt][r] + b2v[nt];
        }
      }
#pragma unroll
      for (int r = 0; r < 4; ++r) {
        float s = y[r][0] + y[r][1] + y[r][2] + y[r][3];
        s += __shfl_xor(s, 1);
        s += __shfl_xor(s, 2);
        s += __shfl_xor(s, 4);
        s += __shfl_xor(s, 8);
        float mu = s * (1.f / 64.f);
        float d0 = y[r][0] - mu, d1 = y[r][1] - mu;
        float d2 = y[r][2] - mu, d3 = y[r][3] - mu;
        float v = d0 * d0 + d1 * d1 + d2 * d2 + d3 * d3;
        v += __shfl_xor(v, 1);
        v += __shfl_xor(v, 2);
        v += __shfl_xor(v, 4);
        v += __shfl_xor(v, 8);
        float iv = rsqrtf(v * (1.f / 64.f) + 1e-5f);
        int nd3 = n0 + gq * 4 + r;
        if (nd3 < npg) {
#pragma unroll
          for (int nt = 0; nt < 4; ++nt)
            xout[xel(nd3, cc + 16 * nt)] =
                (_Float16)((y[r][nt] - mu) * iv * gv[nt] + bv[nt]);
        }
      }
    }
    __syncthreads();
  }

  // ---- 3: species pooling (final x in sA). sBf aliases dead sB; aux
  //         aliases dead sT.
  unsigned short* sBfU = reinterpret_cast<unsigned short*>(sB);
  char* aux = reinterpret_cast<char*>(&sT[0][0]);
  float* sInv = reinterpret_cast<float*>(aux);
  float* sHas = reinterpret_cast<float*>(aux + 1600);
  unsigned* svb = reinterpret_cast<unsigned*>(aux + 3200);
  for (int i = tid; i < n_species + 1; i += 512) sStart[i] = 0;
  for (int i = tid; i < n_species; i += 512) sCnt[i] = 0;
  __syncthreads();
  for (int i = tid; i < npg; i += 512) {
    int s = sp[base + i];
    if (s >= 0 && leaf[base + i] != 0) atomicAdd(&sStart[s + 1], 1);
  }
  __syncthreads();
  if (w == 0) {
    int run = 0;
    for (int chunk = 0; chunk * 64 < n_species + 1; ++chunk) {
      int idx = chunk * 64 + lane;
      int v = (idx < n_species + 1) ? sStart[idx] : 0;
      for (int off = 1; off < 64; off <<= 1) {
        int t2 = __shfl_up(v, off);
        if (lane >= off) v += t2;
      }
      v += run;
      if (idx < n_species + 1) sStart[idx] = v;
      run = __shfl(v, 63);
    }
  }
  __syncthreads();
  for (int i = tid; i < npg; i += 512) {
    int s = sp[base + i];
    if (s >= 0 && leaf[base + i] != 0) {
      int pos = sStart[s] + atomicAdd(&sCnt[s], 1);
      sPar[pos] = i;
    }
  }
  __syncthreads();
  // means: thread per (species, dim-chunk), pad species [n_species,224)->0.
  for (int idx = tid; idx < 224 * 8; idx += 512) {
    int s = idx >> 3, dc = idx & 7;
    float sum[8] = {0.f, 0.f, 0.f, 0.f, 0.f, 0.f, 0.f, 0.f};
    int cntv = 0;
    if (s < n_species) {
      int j0 = sStart[s], j1 = sStart[s + 1];
      cntv = j1 - j0;
      for (int j2 = j0; j2 < j1; ++j2) {
        int nd = sPar[j2];
        half8 v = *reinterpret_cast<const half8*>(
            &sA[nd * 64 + ((dc ^ (nd & 7)) << 3)]);
#pragma unroll
        for (int dd = 0; dd < 8; ++dd) sum[dd] += (float)v[dd];
      }
    }
    float invc = (cntv > 0) ? 1.f / (float)cntv : 0.f;
#pragma unroll
    for (int dd = 0; dd < 8; ++dd) {
      int d = dc * 8 + dd;
      int frag = (s >> 5) * 4 + (d >> 4);
      int ln = ((s >> 3) & 3) * 16 + (d & 15);
      sBfU[frag * 512 + ln * 8 + (s & 7)] = f2bf(sum[dd] * invc);
    }
  }
  if (tid < 7) {
    unsigned bits = 0;
    for (int b = 0; b < 32; ++b) {
      int s = tid * 32 + b;
      if (s < n_species && sStart[s + 1] > sStart[s]) bits |= 1u << b;
    }
    svb[tid] = bits;
  }
  __syncthreads();
  for (int e = tid; e < 400; e += 512) {
    unsigned ccv = 0;
#pragma unroll
    for (int w2 = 0; w2 < 7; ++w2) ccv += __popc(mfbits[e * 8 + w2] & svb[w2]);
    sInv[e] = 1.f / (float)max(ccv, 1u);
    sHas[e] = (ccv > 0) ? 1.f : 0.f;
  }
  __syncthreads();
  // ---- 4: clade-sum MFMA -> gmat (f16), has
  const bf16x8* A = reinterpret_cast<const bf16x8*>(mfA);
  const bf16x8* Bb = reinterpret_cast<const bf16x8*>(sBfU);
  for (int mt = w; mt < 25; mt += 8) {
    bf16x8 af[7];
#pragma unroll
    for (int kt = 0; kt < 7; ++kt) af[kt] = A[(mt * 7 + kt) * 64 + lane];
    f32x4 acc0 = {0.f, 0.f, 0.f, 0.f};
    f32x4 acc1 = {0.f, 0.f, 0.f, 0.f};
    f32x4 acc2 = {0.f, 0.f, 0.f, 0.f};
    f32x4 acc3 = {0.f, 0.f, 0.f, 0.f};
#pragma unroll
    for (int kt = 0; kt < 7; ++kt) {
      const bf16x8* B = Bb + kt * 256 + lane;
      acc0 = __builtin_amdgcn_mfma_f32_16x16x32_bf16(af[kt], B[0], acc0, 0, 0, 0);
      acc1 = __builtin_amdgcn_mfma_f32_16x16x32_bf16(af[kt], B[64], acc1, 0, 0, 0);
      acc2 = __builtin_amdgcn_mfma_f32_16x16x32_bf16(af[kt], B[128], acc2, 0, 0, 0);
      acc3 = __builtin_amdgcn_mfma_f32_16x16x32_bf16(af[kt], B[192], acc3, 0, 0, 0);
    }
    int rbase = mt * 16 + (lane >> 4) * 4;
    int col = lane & 15;
#pragma unroll
    for (int r = 0; r < 4; ++r) {
      int e = rbase + r;
      if (e >= n_edges) continue;
      float inv = sInv[e];
      _Float16* gp = gmat + ((size_t)e * n_gt + g) * 64 + col;
      gp[0] = (_Float16)(acc0[r] * inv);
      gp[16] = (_Float16)(acc1[r] * inv);
      gp[32] = (_Float16)(acc2[r] * inv);
      gp[48] = (_Float16)(acc3[r] * inv);
      if (col == 0) has[(size_t)e * n_gt + g] = sHas[e];
    }
  }
}

// Partial mean/std over a quarter of the gene trees per block.
__global__ __launch_bounds__(256) void k_stat2(const _Float16* __restrict__ gmat,
                                               const float* __restrict__ has,
                                               float* __restrict__ part,
                                               int n_gt) {
  __shared__ float red1[4][64];
  __shared__ float red2[4][64];
  __shared__ float redn[4];
  int b = blockIdx.x;
  int e = b >> 2, q = b & 3;
  int tid = threadIdx.x, w = tid >> 6, lane = tid & 63;
  const _Float16* ge = gmat + ((size_t)e * n_gt + q * 128) * 64;
  const float* he = has + (size_t)e * n_gt + q * 128;
  float S1 = 0.f, S2 = 0.f, nv = 0.f;
  for (int i = w; i < 128; i += 4) {
    float h = he[i];
    float v = (float)ge[i * 64 + lane];
    S1 += h * v;
    S2 += h * v * v;
    nv += h;
  }
  red1[w][lane] = S1;
  red2[w][lane] = S2;
  if (lane == 0) redn[w] = nv;
  __syncthreads();
  if (w == 0) {
    float s1 = 0.f, s2 = 0.f, n_v = 0.f;
#pragma unroll
    for (int j = 0; j < 4; ++j) {
      s1 += red1[j][lane];
      s2 += red2[j][lane];
      n_v += redn[j];
    }
    float* p = part + (size_t)b * 130;
    p[lane] = s1;
    p[64 + lane] = s2;
    if (lane == 0) p[128] = n_v;
  }
}

// Combine the 4 partials per edge and finalize mean/std.
__global__ __launch_bounds__(64) void k_fin(const float* __restrict__ part,
                                            float* __restrict__ out) {
  int e = blockIdx.x;
  int lane = threadIdx.x;
  float s1 = 0.f, s2 = 0.f, n_v = 0.f;
#pragma unroll
  for (int q = 0; q < 4; ++q) {
    const float* p = part + (size_t)(e * 4 + q) * 130;
    s1 += p[lane];
    s2 += p[64 + lane];
    n_v += p[128];
  }
  float mean = s1 / fmaxf(n_v, 1.f);
  float var = (s2 - s1 * s1 / fmaxf(n_v, 1.f)) / fmaxf(n_v - 1.f, 1.f);
  float stdv = (n_v > 1.f) ? sqrtf(fmaxf(var, 0.f)) : 0.f;
  out[(size_t)e * 128 + lane] = (n_v > 0.f) ? mean : 0.f;
  out[(size_t)e * 128 + 64 + lane] = stdv;
}

extern "C" void kernel_launch(void* const* d_in, const int* in_sizes, int n_in,
                              void* d_out, int out_size, void* d_ws, size_t ws_size,
                              hipStream_t stream) {
  (void)n_in; (void)out_size; (void)ws_size;
  const int* edge_index = (const int*)d_in[0];
  const int* sp_ids = (const int*)d_in[1];
  const int* leaf_mask = (const int*)d_in[2];
  const int* clade_mask = (const int*)d_in[4];
  const float* emb = (const float*)d_in[6];
  const float* W1 = (const float*)d_in[7];
  const float* b1 = (const float*)d_in[8];
  const float* W2 = (const float*)d_in[9];
  const float* b2 = (const float*)d_in[10];
  const float* eps = (const float*)d_in[11];
  const float* lng = (const float*)d_in[12];
  const float* lnb = (const float*)d_in[13];
  float* out = (float*)d_out;

  const int n_nodes = in_sizes[1];             // 204288
  const int nE = in_sizes[0] / 2;              // 407552 directed edges
  const int n_species = in_sizes[6] / 64 - 1;  // 200
  const int n_edges = in_sizes[4] / n_species; // 397
  const int n_gt = 512;                        // fixed problem size
  const int npg = n_nodes / n_gt;              // 399 nodes per gene tree

  const int* src = edge_index;       // first half: child ids
  const int* dst = edge_index + nE;  // first half: parent ids

  char* p = (char*)d_ws;
  _Float16* gmat = (_Float16*)p;
  p += ((size_t)n_edges * n_gt * 64 * sizeof(_Float16) + 255ul) & ~255ul;
  float* has = (float*)p;
  p += ((size_t)n_edges * n_gt * sizeof(float) + 255ul) & ~255ul;
  unsigned short* mfA = (unsigned short*)p;
  p += ((size_t)25 * 7 * 512 * sizeof(unsigned short) + 255ul) & ~255ul;
  unsigned* mfbits = (unsigned*)p;
  p += ((size_t)400 * 8 * sizeof(unsigned) + 255ul) & ~255ul;
  float* part = (float*)p;
  p += ((size_t)n_edges * 4 * 130 * sizeof(float) + 255ul) & ~255ul;
  _Float16* wswz = (_Float16*)p;

  k_prep<<<64, 256, 0, stream>>>(clade_mask, W1, W2, mfA, mfbits, wswz,
                                 n_edges, n_species);
  k_tree<<<n_gt, 512, 0, stream>>>(emb, sp_ids, leaf_mask, src, dst, wswz, b1,
                                   b2, eps, lng, lnb, mfA, mfbits, gmat, has,
                                   npg, n_species, n_edges, n_gt);
  k_stat2<<<n_edges * 4, 256, 0, stream>>>(gmat, has, part, n_gt);
  k_fin<<<n_edges, 64, 0, stream>>>(part, out);
}

// Round 21
// 112.728 us; speedup vs baseline: 1.2720x; 1.0287x over previous
//
#include <hip/hip_runtime.h>

// Fixed problem geometry: D=64, n_gt=512, npg=399 nodes/tree, 398 edges/tree.
#define NPG 399

typedef __bf16 bf16x8 __attribute__((ext_vector_type(8)));
typedef _Float16 half8 __attribute__((ext_vector_type(8)));
typedef float f32x4 __attribute__((ext_vector_type(4)));

__device__ __forceinline__ unsigned short f2bf(float f) {
  unsigned u = __float_as_uint(f);
  unsigned r = (u + 0x7FFFu + ((u >> 16) & 1u)) >> 16;
  return (unsigned short)r;
}
// x rows live in LDS as 8 chunks of 8 f16; chunk slot = chunk ^ (node&7).
__device__ __forceinline__ int xel(int node, int dim) {
  return node * 64 + ((((dim >> 3)) ^ (node & 7)) << 3) + (dim & 7);
}

// Build (a) mf A-fragments (bf16, 16x16x32 lane layout) + packed bitmasks,
// (b) f16 frag-swizzled weight fragments in GLOBAL (L2-resident).
__global__ __launch_bounds__(256) void k_prep(const int* __restrict__ clade,
                                              const float* __restrict__ W1,
                                              const float* __restrict__ W2,
                                              unsigned short* __restrict__ mfA,
                                              unsigned* __restrict__ mfbits,
                                              _Float16* __restrict__ wswz,
                                              int n_edges, int n_species) {
  int stride = gridDim.x * 256;
  for (int idx = blockIdx.x * 256 + threadIdx.x; idx < 25 * 7 * 512;
       idx += stride) {
    int fi = idx >> 9, within = idx & 511;
    int mt = fi / 7, kt = fi % 7;
    int l = within >> 3, j = within & 7;
    int e = mt * 16 + (l & 15);
    int s = kt * 32 + ((l >> 4) & 3) * 8 + j;
    unsigned short v = 0;
    if (e < n_edges && s < n_species && clade[(size_t)e * n_species + s] != 0)
      v = 0x3F80;  // bf16(1.0)
    mfA[idx] = v;
  }
  for (int idx = blockIdx.x * 256 + threadIdx.x; idx < 400 * 8; idx += stride) {
    int e = idx >> 3, w = idx & 7;
    unsigned bits = 0;
    if (e < n_edges && w < 7) {
      for (int b = 0; b < 32; ++b) {
        int s = w * 32 + b;
        if (s < n_species && clade[(size_t)e * n_species + s] != 0)
          bits |= 1u << b;
      }
    }
    mfbits[idx] = bits;
  }
  for (int idx = blockIdx.x * 256 + threadIdx.x; idx < 16384; idx += stride) {
    int li = idx >> 12;  // 0..3 = (layer<<1)|mat
    int k = (idx >> 6) & 63, n = idx & 63;
    int frag = (k >> 5) * 4 + (n >> 4);
    int ln = ((k >> 3) & 3) * 16 + (n & 15);
    int j = k & 7;
    int l = li >> 1;
    const float* Ws = (li & 1) ? W2 : W1;
    wswz[li * 4096 + frag * 512 + ln * 8 + j] =
        (_Float16)Ws[l * 4096 + k * 64 + n];
  }
}

// Mega-kernel v12 = r20 + dual-tile interleaving: each wave processes two
// independent tiles' gather/MFMA/LN pipelines simultaneously (doubled ILP on
// the latency-bound LDS chains). Per-wave tile buffer doubled (sT[8][2048]).
__global__ __launch_bounds__(512) void k_tree(
    const float* __restrict__ emb, const int* __restrict__ sp,
    const int* __restrict__ leaf, const int* __restrict__ src,
    const int* __restrict__ dst, const _Float16* __restrict__ wswz,
    const float* __restrict__ b1, const float* __restrict__ b2,
    const float* __restrict__ eps_p, const float* __restrict__ gam,
    const float* __restrict__ bet, const unsigned short* __restrict__ mfA,
    const unsigned* __restrict__ mfbits, _Float16* __restrict__ gmat,
    float* __restrict__ has, int npg, int n_species, int n_edges, int n_gt) {
  __shared__ __attribute__((aligned(16))) _Float16 sA[NPG * 64];
  __shared__ __attribute__((aligned(16))) _Float16 sB[NPG * 64];
  __shared__ __attribute__((aligned(16))) _Float16 sT[8][2048];
  __shared__ int sStart[NPG + 1];
  __shared__ int sChild[NPG - 1];
  __shared__ int sPar[NPG];
  __shared__ int sCnt[NPG];

  int g = blockIdx.x, tid = threadIdx.x;
  int base = g * npg, nEt = npg - 1, ebase = g * nEt;
  int w = tid >> 6, lane = tid & 63;
  int cc = lane & 15, gq = lane >> 4;

  // ---- 0a: zero CSR counters
  for (int i = tid; i < npg + 1; i += 512) sStart[i] = 0;
  for (int i = tid; i < npg; i += 512) sCnt[i] = 0;
  __syncthreads();
  // ---- 0b: emb gather (swizzled chunks), edges + histogram
  for (int idx = tid; idx < npg * 8; idx += 512) {
    int node = idx >> 3, ch = idx & 7;
    int s = sp[base + node];
    int row = (s < 0) ? n_species : s;
    float4 v0 = reinterpret_cast<const float4*>(emb)[row * 16 + ch * 2];
    float4 v1 = reinterpret_cast<const float4*>(emb)[row * 16 + ch * 2 + 1];
    half8 h;
    h[0] = (_Float16)v0.x; h[1] = (_Float16)v0.y;
    h[2] = (_Float16)v0.z; h[3] = (_Float16)v0.w;
    h[4] = (_Float16)v1.x; h[5] = (_Float16)v1.y;
    h[6] = (_Float16)v1.z; h[7] = (_Float16)v1.w;
    *reinterpret_cast<half8*>(&sA[node * 64 + ((ch ^ (node & 7)) << 3)]) = h;
  }
  for (int i = tid; i < nEt; i += 512) {
    int c = src[ebase + i] - base;
    int p = dst[ebase + i] - base;
    sPar[c] = p;
    atomicAdd(&sStart[p + 1], 1);
  }
  __syncthreads();
  // ---- 0c: inclusive scan (wave 0, shfl)
  if (w == 0) {
    int run = 0;
    for (int chunk = 0; chunk * 64 < npg + 1; ++chunk) {
      int idx = chunk * 64 + lane;
      int v = (idx < npg + 1) ? sStart[idx] : 0;
      for (int off = 1; off < 64; off <<= 1) {
        int t2 = __shfl_up(v, off);
        if (lane >= off) v += t2;
      }
      v += run;
      if (idx < npg + 1) sStart[idx] = v;
      run = __shfl(v, 63);
    }
  }
  __syncthreads();
  // ---- 0d: scatter children
  for (int c = tid + 1; c < npg; c += 512) {
    int p = sPar[c];
    int pos = sStart[p] + atomicAdd(&sCnt[p], 1);
    sChild[pos] = c;
  }
  __syncthreads();

  // ---- layers (dual-tile interleaved per wave)
  _Float16* tbA = &sT[w][0];
  _Float16* tbB = &sT[w][1024];
  int t0w = w * 3;
  int t1w = (w == 7) ? 25 : t0w + 3;
  for (int l = 0; l < 2; ++l) {
    const _Float16* xin = l ? sB : sA;
    _Float16* xout = l ? sA : sB;
    const half8* xin8 = reinterpret_cast<const half8*>(xin);
    float e1 = 1.0f + eps_p[l];
    float b1v[4], b2v[4], gv[4], bv[4];
#pragma unroll
    for (int nt = 0; nt < 4; ++nt) {
      b1v[nt] = b1[l * 64 + cc + 16 * nt];
      b2v[nt] = b2[l * 64 + cc + 16 * nt];
      gv[nt] = gam[l * 64 + cc + 16 * nt];
      bv[nt] = bet[l * 64 + cc + 16 * nt];
    }
    const half8* B1 = reinterpret_cast<const half8*>(wswz + (l * 2 + 0) * 4096);
    const half8* B2 = reinterpret_cast<const half8*>(wswz + (l * 2 + 1) * 4096);
    for (int t = t0w; t < t1w; t += 2) {
      bool hasB = (t + 1) < t1w;
      int n0A = t * 16, n0B = n0A + 16;
      // --- dual gather: two independent chains in flight ---
      int nodeA = n0A + cc;
      bool vnA = nodeA < npg;
      int ndA = vnA ? nodeA : 0;
      int j0A = vnA ? sStart[ndA] : 0;
      int cntA = vnA ? (sStart[ndA + 1] - j0A) : 0;
      int nodeB = n0B + cc;
      bool vnB = hasB && nodeB < npg;
      int ndB = vnB ? nodeB : 0;
      int j0B = vnB ? sStart[ndB] : 0;
      int cntB = vnB ? (sStart[ndB + 1] - j0B) : 0;
      half8 sfA0 = xin8[ndA * 8 + (gq ^ (ndA & 7))];
      half8 sfA1 = xin8[ndA * 8 + ((4 + gq) ^ (ndA & 7))];
      half8 sfB0 = xin8[ndB * 8 + (gq ^ (ndB & 7))];
      half8 sfB1 = xin8[ndB * 8 + ((4 + gq) ^ (ndB & 7))];
      bool hpA = vnA && nodeA > 0;
      int prA = hpA ? sPar[ndA] : 0;
      bool hpB = vnB && nodeB > 0;
      int prB = hpB ? sPar[ndB] : 0;
      half8 ppA0 = xin8[prA * 8 + (gq ^ (prA & 7))];
      half8 ppA1 = xin8[prA * 8 + ((4 + gq) ^ (prA & 7))];
      half8 ppB0 = xin8[prB * 8 + (gq ^ (prB & 7))];
      half8 ppB1 = xin8[prB * 8 + ((4 + gq) ^ (prB & 7))];
      float aA0[8], aA1[8], aB0[8], aB1[8];
#pragma unroll
      for (int d = 0; d < 8; ++d) {
        aA0[d] = e1 * (float)sfA0[d] + (hpA ? (float)ppA0[d] : 0.f);
        aA1[d] = e1 * (float)sfA1[d] + (hpA ? (float)ppA1[d] : 0.f);
        aB0[d] = e1 * (float)sfB0[d] + (hpB ? (float)ppB0[d] : 0.f);
        aB1[d] = e1 * (float)sfB1[d] + (hpB ? (float)ppB1[d] : 0.f);
      }
      int cm = max(cntA, cntB);
#pragma unroll
      for (int off = 1; off < 64; off <<= 1) cm = max(cm, __shfl_xor(cm, off));
      cm = __builtin_amdgcn_readfirstlane(cm);
      for (int k = 0; k < cm; ++k) {
        int jA = (k < cntA) ? (j0A + k) : 0;
        int jB = (k < cntB) ? (j0B + k) : 0;
        int cA = sChild[jA];
        int cB = sChild[jB];
        half8 vA0 = xin8[cA * 8 + (gq ^ (cA & 7))];
        half8 vA1 = xin8[cA * 8 + ((4 + gq) ^ (cA & 7))];
        half8 vB0 = xin8[cB * 8 + (gq ^ (cB & 7))];
        half8 vB1 = xin8[cB * 8 + ((4 + gq) ^ (cB & 7))];
        if (k < cntA) {
#pragma unroll
          for (int d = 0; d < 8; ++d) {
            aA0[d] += (float)vA0[d];
            aA1[d] += (float)vA1[d];
          }
        }
        if (k < cntB) {
#pragma unroll
          for (int d = 0; d < 8; ++d) {
            aB0[d] += (float)vB0[d];
            aB1[d] += (float)vB1[d];
          }
        }
      }
      half8 fA0, fA1, fB0, fB1;
#pragma unroll
      for (int d = 0; d < 8; ++d) {
        fA0[d] = (_Float16)aA0[d];
        fA1[d] = (_Float16)aA1[d];
        fB0[d] = (_Float16)aB0[d];
        fB1[d] = (_Float16)aB1[d];
      }
      // --- MFMA 1 (interleaved A/B) + relu -> per-wave tile buffers ---
      f32x4 tA[4], tB[4];
#pragma unroll
      for (int nt = 0; nt < 4; ++nt) {
        tA[nt] = (f32x4){0.f, 0.f, 0.f, 0.f};
        tB[nt] = (f32x4){0.f, 0.f, 0.f, 0.f};
      }
#pragma unroll
      for (int nt = 0; nt < 4; ++nt) {
        half8 w0 = B1[nt * 64 + lane];
        half8 w1 = B1[(4 + nt) * 64 + lane];
        tA[nt] = __builtin_amdgcn_mfma_f32_16x16x32_f16(fA0, w0, tA[nt], 0, 0, 0);
        tB[nt] = __builtin_amdgcn_mfma_f32_16x16x32_f16(fB0, w0, tB[nt], 0, 0, 0);
        tA[nt] = __builtin_amdgcn_mfma_f32_16x16x32_f16(fA1, w1, tA[nt], 0, 0, 0);
        tB[nt] = __builtin_amdgcn_mfma_f32_16x16x32_f16(fB1, w1, tB[nt], 0, 0, 0);
      }
#pragma unroll
      for (int nt = 0; nt < 4; ++nt)
#pragma unroll
        for (int r = 0; r < 4; ++r) {
          int m = gq * 4 + r;
          int off = m * 64 + ((cc + 16 * nt) ^ ((m & 7) << 3));
          tbA[off] = (_Float16)fmaxf(tA[nt][r] + b1v[nt], 0.f);
          tbB[off] = (_Float16)fmaxf(tB[nt][r] + b1v[nt], 0.f);
        }
      int sw = (cc & 7) << 3;
      half8 cA0 =
          *reinterpret_cast<const half8*>(&tbA[cc * 64 + ((gq * 8) ^ sw)]);
      half8 cA1 =
          *reinterpret_cast<const half8*>(&tbA[cc * 64 + ((32 + gq * 8) ^ sw)]);
      half8 cB0 =
          *reinterpret_cast<const half8*>(&tbB[cc * 64 + ((gq * 8) ^ sw)]);
      half8 cB1 =
          *reinterpret_cast<const half8*>(&tbB[cc * 64 + ((32 + gq * 8) ^ sw)]);
      f32x4 hA[4], hB[4];
#pragma unroll
      for (int nt = 0; nt < 4; ++nt) {
        hA[nt] = (f32x4){0.f, 0.f, 0.f, 0.f};
        hB[nt] = (f32x4){0.f, 0.f, 0.f, 0.f};
      }
#pragma unroll
      for (int nt = 0; nt < 4; ++nt) {
        half8 w0 = B2[nt * 64 + lane];
        half8 w1 = B2[(4 + nt) * 64 + lane];
        hA[nt] = __builtin_amdgcn_mfma_f32_16x16x32_f16(cA0, w0, hA[nt], 0, 0, 0);
        hB[nt] = __builtin_amdgcn_mfma_f32_16x16x32_f16(cB0, w0, hB[nt], 0, 0, 0);
        hA[nt] = __builtin_amdgcn_mfma_f32_16x16x32_f16(cA1, w1, hA[nt], 0, 0, 0);
        hB[nt] = __builtin_amdgcn_mfma_f32_16x16x32_f16(cB1, w1, hB[nt], 0, 0, 0);
      }
      // --- residual + LayerNorm (f32), A/B interleaved ---
      float yA[4][4], yB[4][4];
#pragma unroll
      for (int r = 0; r < 4; ++r) {
        int nA3 = n0A + gq * 4 + r;
        bool v3A = nA3 < npg;
        int nsA = v3A ? nA3 : 0;
        int nB3 = n0B + gq * 4 + r;
        bool v3B = hasB && nB3 < npg;
        int nsB = v3B ? nB3 : 0;
#pragma unroll
        for (int nt = 0; nt < 4; ++nt) {
          float xvA = (float)xin[xel(nsA, cc + 16 * nt)];
          float xvB = (float)xin[xel(nsB, cc + 16 * nt)];
          yA[r][nt] = (v3A ? xvA : 0.f) + hA[nt][r] + b2v[nt];
          yB[r][nt] = (v3B ? xvB : 0.f) + hB[nt][r] + b2v[nt];
        }
      }
#pragma unroll
      for (int r = 0; r < 4; ++r) {
        float sa = yA[r][0] + yA[r][1] + yA[r][2] + yA[r][3];
        float sb = yB[r][0] + yB[r][1] + yB[r][2] + yB[r][3];
        sa += __shfl_xor(sa, 1); sb += __shfl_xor(sb, 1);
        sa += __shfl_xor(sa, 2); sb += __shfl_xor(sb, 2);
        sa += __shfl_xor(sa, 4); sb += __shfl_xor(sb, 4);
        sa += __shfl_xor(sa, 8); sb += __shfl_xor(sb, 8);
        float muA = sa * (1.f / 64.f), muB = sb * (1.f / 64.f);
        float dA0 = yA[r][0] - muA, dA1 = yA[r][1] - muA;
        float dA2 = yA[r][2] - muA, dA3 = yA[r][3] - muA;
        float dB0 = yB[r][0] - muB, dB1 = yB[r][1] - muB;
        float dB2 = yB[r][2] - muB, dB3 = yB[r][3] - muB;
        float va = dA0 * dA0 + dA1 * dA1 + dA2 * dA2 + dA3 * dA3;
        float vb = dB0 * dB0 + dB1 * dB1 + dB2 * dB2 + dB3 * dB3;
        va += __shfl_xor(va, 1); vb += __shfl_xor(vb, 1);
        va += __shfl_xor(va, 2); vb += __shfl_xor(vb, 2);
        va += __shfl_xor(va, 4); vb += __shfl_xor(vb, 4);
        va += __shfl_xor(va, 8); vb += __shfl_xor(vb, 8);
        float ivA = rsqrtf(va * (1.f / 64.f) + 1e-5f);
        float ivB = rsqrtf(vb * (1.f / 64.f) + 1e-5f);
        int nA3 = n0A + gq * 4 + r;
        if (nA3 < npg) {
#pragma unroll
          for (int nt = 0; nt < 4; ++nt)
            xout[xel(nA3, cc + 16 * nt)] =
                (_Float16)((yA[r][nt] - muA) * ivA * gv[nt] + bv[nt]);
        }
        int nB3 = n0B + gq * 4 + r;
        if (hasB && nB3 < npg) {
#pragma unroll
          for (int nt = 0; nt < 4; ++nt)
            xout[xel(nB3, cc + 16 * nt)] =
                (_Float16)((yB[r][nt] - muB) * ivB * gv[nt] + bv[nt]);
        }
      }
    }
    __syncthreads();
  }

  // ---- 3: species pooling (final x in sA). sBf aliases dead sB; aux
  //         aliases dead sT.
  unsigned short* sBfU = reinterpret_cast<unsigned short*>(sB);
  char* aux = reinterpret_cast<char*>(&sT[0][0]);
  float* sInv = reinterpret_cast<float*>(aux);
  float* sHas = reinterpret_cast<float*>(aux + 1600);
  unsigned* svb = reinterpret_cast<unsigned*>(aux + 3200);
  for (int i = tid; i < n_species + 1; i += 512) sStart[i] = 0;
  for (int i = tid; i < n_species; i += 512) sCnt[i] = 0;
  __syncthreads();
  for (int i = tid; i < npg; i += 512) {
    int s = sp[base + i];
    if (s >= 0 && leaf[base + i] != 0) atomicAdd(&sStart[s + 1], 1);
  }
  __syncthreads();
  if (w == 0) {
    int run = 0;
    for (int chunk = 0; chunk * 64 < n_species + 1; ++chunk) {
      int idx = chunk * 64 + lane;
      int v = (idx < n_species + 1) ? sStart[idx] : 0;
      for (int off = 1; off < 64; off <<= 1) {
        int t2 = __shfl_up(v, off);
        if (lane >= off) v += t2;
      }
      v += run;
      if (idx < n_species + 1) sStart[idx] = v;
      run = __shfl(v, 63);
    }
  }
  __syncthreads();
  for (int i = tid; i < npg; i += 512) {
    int s = sp[base + i];
    if (s >= 0 && leaf[base + i] != 0) {
      int pos = sStart[s] + atomicAdd(&sCnt[s], 1);
      sPar[pos] = i;
    }
  }
  __syncthreads();
  // means: thread per (species, dim-chunk), pad species [n_species,224)->0.
  for (int idx = tid; idx < 224 * 8; idx += 512) {
    int s = idx >> 3, dc = idx & 7;
    float sum[8] = {0.f, 0.f, 0.f, 0.f, 0.f, 0.f, 0.f, 0.f};
    int cntv = 0;
    if (s < n_species) {
      int j0 = sStart[s], j1 = sStart[s + 1];
      cntv = j1 - j0;
      for (int j2 = j0; j2 < j1; ++j2) {
        int nd = sPar[j2];
        half8 v = *reinterpret_cast<const half8*>(
            &sA[nd * 64 + ((dc ^ (nd & 7)) << 3)]);
#pragma unroll
        for (int dd = 0; dd < 8; ++dd) sum[dd] += (float)v[dd];
      }
    }
    float invc = (cntv > 0) ? 1.f / (float)cntv : 0.f;
#pragma unroll
    for (int dd = 0; dd < 8; ++dd) {
      int d = dc * 8 + dd;
      int frag = (s >> 5) * 4 + (d >> 4);
      int ln = ((s >> 3) & 3) * 16 + (d & 15);
      sBfU[frag * 512 + ln * 8 + (s & 7)] = f2bf(sum[dd] * invc);
    }
  }
  if (tid < 7) {
    unsigned bits = 0;
    for (int b = 0; b < 32; ++b) {
      int s = tid * 32 + b;
      if (s < n_species && sStart[s + 1] > sStart[s]) bits |= 1u << b;
    }
    svb[tid] = bits;
  }
  __syncthreads();
  for (int e = tid; e < 400; e += 512) {
    unsigned ccv = 0;
#pragma unroll
    for (int w2 = 0; w2 < 7; ++w2) ccv += __popc(mfbits[e * 8 + w2] & svb[w2]);
    sInv[e] = 1.f / (float)max(ccv, 1u);
    sHas[e] = (ccv > 0) ? 1.f : 0.f;
  }
  __syncthreads();
  // ---- 4: clade-sum MFMA -> gmat (f16), has
  const bf16x8* A = reinterpret_cast<const bf16x8*>(mfA);
  const bf16x8* Bb = reinterpret_cast<const bf16x8*>(sBfU);
  for (int mt = w; mt < 25; mt += 8) {
    bf16x8 af[7];
#pragma unroll
    for (int kt = 0; kt < 7; ++kt) af[kt] = A[(mt * 7 + kt) * 64 + lane];
    f32x4 acc0 = {0.f, 0.f, 0.f, 0.f};
    f32x4 acc1 = {0.f, 0.f, 0.f, 0.f};
    f32x4 acc2 = {0.f, 0.f, 0.f, 0.f};
    f32x4 acc3 = {0.f, 0.f, 0.f, 0.f};
#pragma unroll
    for (int kt = 0; kt < 7; ++kt) {
      const bf16x8* B = Bb + kt * 256 + lane;
      acc0 = __builtin_amdgcn_mfma_f32_16x16x32_bf16(af[kt], B[0], acc0, 0, 0, 0);
      acc1 = __builtin_amdgcn_mfma_f32_16x16x32_bf16(af[kt], B[64], acc1, 0, 0, 0);
      acc2 = __builtin_amdgcn_mfma_f32_16x16x32_bf16(af[kt], B[128], acc2, 0, 0, 0);
      acc3 = __builtin_amdgcn_mfma_f32_16x16x32_bf16(af[kt], B[192], acc3, 0, 0, 0);
    }
    int rbase = mt * 16 + (lane >> 4) * 4;
    int col = lane & 15;
#pragma unroll
    for (int r = 0; r < 4; ++r) {
      int e = rbase + r;
      if (e >= n_edges) continue;
      float inv = sInv[e];
      _Float16* gp = gmat + ((size_t)e * n_gt + g) * 64 + col;
      gp[0] = (_Float16)(acc0[r] * inv);
      gp[16] = (_Float16)(acc1[r] * inv);
      gp[32] = (_Float16)(acc2[r] * inv);
      gp[48] = (_Float16)(acc3[r] * inv);
      if (col == 0) has[(size_t)e * n_gt + g] = sHas[e];
    }
  }
}

// Partial mean/std over a quarter of the gene trees per block.
__global__ __launch_bounds__(256) void k_stat2(const _Float16* __restrict__ gmat,
                                               const float* __restrict__ has,
                                               float* __restrict__ part,
                                               int n_gt) {
  __shared__ float red1[4][64];
  __shared__ float red2[4][64];
  __shared__ float redn[4];
  int b = blockIdx.x;
  int e = b >> 2, q = b & 3;
  int tid = threadIdx.x, w = tid >> 6, lane = tid & 63;
  const _Float16* ge = gmat + ((size_t)e * n_gt + q * 128) * 64;
  const float* he = has + (size_t)e * n_gt + q * 128;
  float S1 = 0.f, S2 = 0.f, nv = 0.f;
  for (int i = w; i < 128; i += 4) {
    float h = he[i];
    float v = (float)ge[i * 64 + lane];
    S1 += h * v;
    S2 += h * v * v;
    nv += h;
  }
  red1[w][lane] = S1;
  red2[w][lane] = S2;
  if (lane == 0) redn[w] = nv;
  __syncthreads();
  if (w == 0) {
    float s1 = 0.f, s2 = 0.f, n_v = 0.f;
#pragma unroll
    for (int j = 0; j < 4; ++j) {
      s1 += red1[j][lane];
      s2 += red2[j][lane];
      n_v += redn[j];
    }
    float* p = part + (size_t)b * 130;
    p[lane] = s1;
    p[64 + lane] = s2;
    if (lane == 0) p[128] = n_v;
  }
}

// Combine the 4 partials per edge and finalize mean/std.
__global__ __launch_bounds__(64) void k_fin(const float* __restrict__ part,
                                            float* __restrict__ out) {
  int e = blockIdx.x;
  int lane = threadIdx.x;
  float s1 = 0.f, s2 = 0.f, n_v = 0.f;
#pragma unroll
  for (int q = 0; q < 4; ++q) {
    const float* p = part + (size_t)(e * 4 + q) * 130;
    s1 += p[lane];
    s2 += p[64 + lane];
    n_v += p[128];
  }
  float mean = s1 / fmaxf(n_v, 1.f);
  float var = (s2 - s1 * s1 / fmaxf(n_v, 1.f)) / fmaxf(n_v - 1.f, 1.f);
  float stdv = (n_v > 1.f) ? sqrtf(fmaxf(var, 0.f)) : 0.f;
  out[(size_t)e * 128 + lane] = (n_v > 0.f) ? mean : 0.f;
  out[(size_t)e * 128 + 64 + lane] = stdv;
}

extern "C" void kernel_launch(void* const* d_in, const int* in_sizes, int n_in,
                              void* d_out, int out_size, void* d_ws, size_t ws_size,
                              hipStream_t stream) {
  (void)n_in; (void)out_size; (void)ws_size;
  const int* edge_index = (const int*)d_in[0];
  const int* sp_ids = (const int*)d_in[1];
  const int* leaf_mask = (const int*)d_in[2];
  const int* clade_mask = (const int*)d_in[4];
  const float* emb = (const float*)d_in[6];
  const float* W1 = (const float*)d_in[7];
  const float* b1 = (const float*)d_in[8];
  const float* W2 = (const float*)d_in[9];
  const float* b2 = (const float*)d_in[10];
  const float* eps = (const float*)d_in[11];
  const float* lng = (const float*)d_in[12];
  const float* lnb = (const float*)d_in[13];
  float* out = (float*)d_out;

  const int n_nodes = in_sizes[1];             // 204288
  const int nE = in_sizes[0] / 2;              // 407552 directed edges
  const int n_species = in_sizes[6] / 64 - 1;  // 200
  const int n_edges = in_sizes[4] / n_species; // 397
  const int n_gt = 512;                        // fixed problem size
  const int npg = n_nodes / n_gt;              // 399 nodes per gene tree

  const int* src = edge_index;       // first half: child ids
  const int* dst = edge_index + nE;  // first half: parent ids

  char* p = (char*)d_ws;
  _Float16* gmat = (_Float16*)p;
  p += ((size_t)n_edges * n_gt * 64 * sizeof(_Float16) + 255ul) & ~255ul;
  float* has = (float*)p;
  p += ((size_t)n_edges * n_gt * sizeof(float) + 255ul) & ~255ul;
  unsigned short* mfA = (unsigned short*)p;
  p += ((size_t)25 * 7 * 512 * sizeof(unsigned short) + 255ul) & ~255ul;
  unsigned* mfbits = (unsigned*)p;
  p += ((size_t)400 * 8 * sizeof(unsigned) + 255ul) & ~255ul;
  float* part = (float*)p;
  p += ((size_t)n_edges * 4 * 130 * sizeof(float) + 255ul) & ~255ul;
  _Float16* wswz = (_Float16*)p;

  k_prep<<<64, 256, 0, stream>>>(clade_mask, W1, W2, mfA, mfbits, wswz,
                                 n_edges, n_species);
  k_tree<<<n_gt, 512, 0, stream>>>(emb, sp_ids, leaf_mask, src, dst, wswz, b1,
                                   b2, eps, lng, lnb, mfA, mfbits, gmat, has,
                                   npg, n_species, n_edges, n_gt);
  k_stat2<<<n_edges * 4, 256, 0, stream>>>(gmat, has, part, n_gt);
  k_fin<<<n_edges, 64, 0, stream>>>(part, out);
}